// Round 1
// baseline (436.812 us; speedup 1.0000x reference)
//
#include <hip/hip_runtime.h>

typedef float f32x4 __attribute__((ext_vector_type(4)));
typedef short s16x4 __attribute__((ext_vector_type(4)));
typedef short s16x8 __attribute__((ext_vector_type(8)));

__device__ __forceinline__ short f2bf(float f) {
    union { float f; unsigned u; } c; c.f = f;
    return (short)((c.u + 0x7FFFu + ((c.u >> 16) & 1u)) >> 16);
}

// 16B-granular XOR swizzle on a short index: spreads 256B/128B-strided rows
// across banks (guide §6 G4: byte ^= ((row&7)<<4)  ==  short_idx ^= ((row&7)<<3)).
__device__ __forceinline__ int swz128(int row, int col) {
    return row * 128 + (col ^ ((row & 7) << 3));
}
__device__ __forceinline__ int swz64(int row, int col) {
    return row * 64 + (col ^ ((row & 7) << 3));
}

// ---- prep: transpose 5 fp32 [k][n] weights into bf16 [n][k] in workspace ----
__global__ __launch_bounds__(256) void k_prep(
    const float* __restrict__ Wq, const float* __restrict__ Wk,
    const float* __restrict__ Wv, const float* __restrict__ Wot,
    const float* __restrict__ Wtg, short* __restrict__ Wt) {
    const float* srcs[5] = {Wq, Wk, Wv, Wot, Wtg};
    const float* W = srcs[blockIdx.x];
    short* dst = Wt + blockIdx.x * 16384;
    const int t = threadIdx.x;
#pragma unroll 4
    for (int i = 0; i < 64; ++i) {
        int idx = i * 256 + t;
        int k = idx >> 7, n = idx & 127;
        dst[n * 128 + k] = f2bf(W[idx]);
    }
}

// B-fragment from pre-transposed bf16 weight: Wt[n][k], n=ni*16+m, k=kk*32+quad*8
__device__ __forceinline__ s16x8 wfrag(const short* __restrict__ Wt,
                                       int ni, int kk, int m, int quad) {
    return *(const s16x8*)(Wt + (ni * 16 + m) * 128 + kk * 32 + quad * 8);
}

// A-fragment loaded straight from a global fp32 [64][128] tile (row = own-band row).
__device__ __forceinline__ s16x8 ldfrag(const float* __restrict__ src, int row, int col) {
    f32x4 x0 = *(const f32x4*)(src + row * 128 + col);
    f32x4 x1 = *(const f32x4*)(src + row * 128 + col + 4);
    s16x8 p;
    p[0] = f2bf(x0[0]); p[1] = f2bf(x0[1]); p[2] = f2bf(x0[2]); p[3] = f2bf(x0[3]);
    p[4] = f2bf(x1[0]); p[5] = f2bf(x1[1]); p[6] = f2bf(x1[2]); p[7] = f2bf(x1[3]);
    return p;
}

__global__ __launch_bounds__(256, 3) void k_main(
    const float* __restrict__ XQ, const float* __restrict__ XK,
    const float* __restrict__ Tgt, const short* __restrict__ Wt,
    const float* __restrict__ bq, const float* __restrict__ bk,
    const float* __restrict__ bv, const float* __restrict__ bot,
    const float* __restrict__ btg,
    const float* __restrict__ g_time, const float* __restrict__ b_time,
    const float* __restrict__ g_tgt, const float* __restrict__ b_tgt,
    float* __restrict__ out0, float* __restrict__ out1, float* __restrict__ out2) {
    const int bn = blockIdx.x;
    const int t = threadIdx.x;
    const int w = t >> 6, lane = t & 63, m = lane & 15, quad = lane >> 4;
    const int r0 = w * 16;  // this wave's 16-row band

    // LDS: 16K + 16K + 8K + 8K = 48 KiB -> 3 blocks/CU.
    __shared__ short Rk[64 * 128];    // q scatter (own band) -> k -> tv
    __shared__ short Rv[128 * 64];    // v^T        -> ct (as [64][128])
    __shared__ short Rs[4][16 * 64];  // per-wave S band (private, no barrier)
    __shared__ short Rt[4][16 * 64];  // per-wave Tgt^T head slice (private)

    const size_t base = (size_t)bn * 8192;
    const short* Wqt = Wt;
    const short* Wkt = Wt + 16384;
    const short* Wvt = Wt + 32768;
    const short* Wot_t = Wt + 49152;
    const short* Wtg_t = Wt + 65536;
    short* myRs = Rs[w];
    short* myRt = Rt[w];

    // ---------- q = XQ@Wq + bq : frags direct from global, scatter into own
    // Rk band, read per-head A-frags back to regs (wave-private, NO barrier) --
    s16x8 qf[8];
    {
        s16x8 a[4];
#pragma unroll
        for (int kk = 0; kk < 4; ++kk)
            a[kk] = ldfrag(XQ + base, r0 + m, kk * 32 + quad * 8);
        f32x4 accq[8];
#pragma unroll
        for (int ni = 0; ni < 8; ++ni) {
            accq[ni] = (f32x4){0.f, 0.f, 0.f, 0.f};
#pragma unroll
            for (int kk = 0; kk < 4; ++kk)
                accq[ni] = __builtin_amdgcn_mfma_f32_16x16x32_bf16(
                    a[kk], wfrag(Wqt, ni, kk, m, quad), accq[ni], 0, 0, 0);
        }
#pragma unroll
        for (int ni = 0; ni < 8; ++ni) {
            const float bb = bq[ni * 16 + m];
#pragma unroll
            for (int r = 0; r < 4; ++r)
                Rk[swz128(r0 + quad * 4 + r, ni * 16 + m)] = f2bf(accq[ni][r] + bb);
        }
        // read back own band in A-layout; only quads 0-1 carry real K (dk=16)
#pragma unroll
        for (int h = 0; h < 8; ++h) {
            qf[h] = (s16x8){0, 0, 0, 0, 0, 0, 0, 0};
            if (quad < 2)
                qf[h] = *(const s16x8*)(Rk + swz128(r0 + m, h * 16 + quad * 8));
        }
    }

    // ---------- k,v = XK@{Wk,Wv} + bias : frags direct from global ----------
    {
        s16x8 a[4];
#pragma unroll
        for (int kk = 0; kk < 4; ++kk)
            a[kk] = ldfrag(XK + base, r0 + m, kk * 32 + quad * 8);
        f32x4 acck[8], accv[8];
#pragma unroll
        for (int ni = 0; ni < 8; ++ni) {
            acck[ni] = (f32x4){0.f, 0.f, 0.f, 0.f};
            accv[ni] = (f32x4){0.f, 0.f, 0.f, 0.f};
#pragma unroll
            for (int kk = 0; kk < 4; ++kk) {
                acck[ni] = __builtin_amdgcn_mfma_f32_16x16x32_bf16(
                    a[kk], wfrag(Wkt, ni, kk, m, quad), acck[ni], 0, 0, 0);
                accv[ni] = __builtin_amdgcn_mfma_f32_16x16x32_bf16(
                    a[kk], wfrag(Wvt, ni, kk, m, quad), accv[ni], 0, 0, 0);
            }
        }
        // k row-major into own band (overwrites q scatter AFTER qf reads: same
        // wave, program order). v transposed into Rv: v^T[d][key].
#pragma unroll
        for (int ni = 0; ni < 8; ++ni) {
            const float bbk = bk[ni * 16 + m];
            const float bbv = bv[ni * 16 + m];
#pragma unroll
            for (int r = 0; r < 4; ++r) {
                Rk[swz128(r0 + quad * 4 + r, ni * 16 + m)] = f2bf(acck[ni][r] + bbk);
                Rv[swz64(ni * 16 + m, r0 + quad * 4 + r)] = f2bf(accv[ni][r] + bbv);
            }
        }
    }
    __syncthreads();  // barrier #1: k, v^T visible to all waves

    // ---------- per-head: S = q k^T / 4 ; tv += S v ; ct += S tk -----------
    // Zero barriers in this loop: Rs/Rt are wave-private, Rk/Rv are read-only.
    f32x4 accv8[8], acct8[8];
    const s16x8 zfrag = (s16x8){0, 0, 0, 0, 0, 0, 0, 0};
    float* o0 = out0 + (size_t)bn * 32768;
#pragma unroll
    for (int h = 0; h < 8; ++h) {
        // stage this wave's private Tgt^T slice [16][64] (4 x float4 per lane)
        {
            const int c0 = (lane & 3) * 4;
#pragma unroll
            for (int it = 0; it < 4; ++it) {
                const int key = (lane >> 2) + it * 16;
                f32x4 x = *(const f32x4*)(Tgt + base + key * 128 + h * 16 + c0);
#pragma unroll
                for (int r = 0; r < 4; ++r) myRt[swz64(c0 + r, key)] = f2bf(x[r]);
            }
        }

        // S for own 16-row band (K=32 MFMA, upper 16 k zeroed)
        const s16x8 aq = qf[h];
#pragma unroll
        for (int nj = 0; nj < 4; ++nj) {
            s16x8 bk_ = zfrag;
            if (quad < 2)
                bk_ = *(const s16x8*)(Rk + swz128(nj * 16 + m, h * 16 + quad * 8));
            f32x4 s = __builtin_amdgcn_mfma_f32_16x16x32_bf16(
                aq, bk_, (f32x4){0.f, 0.f, 0.f, 0.f}, 0, 0, 0);
#pragma unroll
            for (int r = 0; r < 4; ++r) {
                const int row = r0 + quad * 4 + r;
                const float sval = s[r] * 0.25f;
                o0[h * 4096 + row * 64 + nj * 16 + m] = sval;  // async, never drained
                myRs[swz64(quad * 4 + r, nj * 16 + m)] = f2bf(sval);
            }
        }

        // tv_h = S @ v_h ; ct_h = S @ tk_h  (S read back from own private band)
        accv8[h] = (f32x4){0.f, 0.f, 0.f, 0.f};
        acct8[h] = (f32x4){0.f, 0.f, 0.f, 0.f};
#pragma unroll
        for (int kk = 0; kk < 2; ++kk) {
            s16x8 sa  = *(const s16x8*)(myRs + swz64(m, kk * 32 + quad * 8));
            s16x8 bv_ = *(const s16x8*)(Rv + swz64(h * 16 + m, kk * 32 + quad * 8));
            s16x8 bt_ = *(const s16x8*)(myRt + swz64(m, kk * 32 + quad * 8));
            accv8[h] = __builtin_amdgcn_mfma_f32_16x16x32_bf16(sa, bv_, accv8[h], 0, 0, 0);
            acct8[h] = __builtin_amdgcn_mfma_f32_16x16x32_bf16(sa, bt_, acct8[h], 0, 0, 0);
        }
    }
    __syncthreads();  // barrier #2: all cross-wave Rk/Rv reads done before reuse

    // ---------- tv -> Rk band, ct -> Rv band (A-layout [64][128], own band) --
    short* Rct = Rv;  // reuse as raw [64][128]
#pragma unroll
    for (int h = 0; h < 8; ++h) {
#pragma unroll
        for (int r = 0; r < 4; ++r) {
            const int row = r0 + quad * 4 + r;
            Rk[swz128(row, h * 16 + m)]  = f2bf(accv8[h][r]);
            Rct[swz128(row, h * 16 + m)] = f2bf(acct8[h][r]);
        }
    }
    // own band write -> own band read: wave-private, no barrier

    // ---------- output projections + LayerNorm ------------------------------
#pragma unroll
    for (int br = 0; br < 2; ++br) {
        const short* sA = br == 0 ? Rk : Rct;
        const short* Wp = br == 0 ? Wot_t : Wtg_t;
        const float* bias = br == 0 ? bot : btg;
        const float* gam = br == 0 ? g_time : g_tgt;
        const float* bet = br == 0 ? b_time : b_tgt;
        float* outp = (br == 0 ? out1 : out2) + base;
        const float* resid = br == 0 ? XQ + base : nullptr;

        s16x8 a[4];
#pragma unroll
        for (int kk = 0; kk < 4; ++kk)
            a[kk] = *(const s16x8*)(sA + swz128(r0 + m, kk * 32 + quad * 8));
        f32x4 acc[8];
#pragma unroll
        for (int ni = 0; ni < 8; ++ni) {
            acc[ni] = (f32x4){0.f, 0.f, 0.f, 0.f};
#pragma unroll
            for (int kk = 0; kk < 4; ++kk)
                acc[ni] = __builtin_amdgcn_mfma_f32_16x16x32_bf16(
                    a[kk], wfrag(Wp, ni, kk, m, quad), acc[ni], 0, 0, 0);
        }
        float y[8][4];
        float s1[4] = {0.f, 0.f, 0.f, 0.f}, s2[4] = {0.f, 0.f, 0.f, 0.f};
#pragma unroll
        for (int ni = 0; ni < 8; ++ni) {
            const int col = ni * 16 + m;
            const float bb = bias[col];
#pragma unroll
            for (int r = 0; r < 4; ++r) {
                const int row = r0 + quad * 4 + r;
                float v = acc[ni][r] + bb;
                if (resid) v += resid[row * 128 + col];
                y[ni][r] = v;
                s1[r] += v;
                s2[r] += v * v;
            }
        }
#pragma unroll
        for (int mask = 1; mask < 16; mask <<= 1) {
#pragma unroll
            for (int r = 0; r < 4; ++r) {
                s1[r] += __shfl_xor(s1[r], mask, 64);
                s2[r] += __shfl_xor(s2[r], mask, 64);
            }
        }
        float mu[4], rstd[4];
#pragma unroll
        for (int r = 0; r < 4; ++r) {
            mu[r] = s1[r] * (1.0f / 128.0f);
            float var = s2[r] * (1.0f / 128.0f) - mu[r] * mu[r];
            rstd[r] = rsqrtf(var + 1e-5f);
        }
#pragma unroll
        for (int ni = 0; ni < 8; ++ni) {
            const int col = ni * 16 + m;
            const float g = gam[col], bb = bet[col];
#pragma unroll
            for (int r = 0; r < 4; ++r) {
                const int row = r0 + quad * 4 + r;
                outp[row * 128 + col] = (y[ni][r] - mu[r]) * rstd[r] * g + bb;
            }
        }
    }
}

extern "C" void kernel_launch(void* const* d_in, const int* in_sizes, int n_in,
                              void* d_out, int out_size, void* d_ws, size_t ws_size,
                              hipStream_t stream) {
    const float* XQ  = (const float*)d_in[0];
    const float* XK  = (const float*)d_in[1];
    const float* Tgt = (const float*)d_in[2];
    const float* Wq  = (const float*)d_in[3];
    const float* bq  = (const float*)d_in[4];
    const float* Wk  = (const float*)d_in[5];
    const float* bk  = (const float*)d_in[6];
    const float* Wv  = (const float*)d_in[7];
    const float* bv  = (const float*)d_in[8];
    const float* Wot = (const float*)d_in[9];
    const float* bot = (const float*)d_in[10];
    const float* Wtg = (const float*)d_in[11];
    const float* btg = (const float*)d_in[12];
    const float* g_time = (const float*)d_in[13];
    const float* b_time = (const float*)d_in[14];
    const float* g_tgt  = (const float*)d_in[15];
    const float* b_tgt  = (const float*)d_in[16];

    const int BN = in_sizes[0] / 8192;  // B*N

    short* Wt = (short*)d_ws;  // 5 * 128 * 128 bf16 = 160 KB

    float* out0 = (float*)d_out;
    float* out1 = out0 + (size_t)BN * 32768;
    float* out2 = out1 + (size_t)BN * 8192;

    k_prep<<<5, 256, 0, stream>>>(Wq, Wk, Wv, Wot, Wtg, Wt);
    k_main<<<BN, 256, 0, stream>>>(XQ, XK, Tgt, Wt, bq, bk, bv, bot, btg,
                                   g_time, b_time, g_tgt, b_tgt,
                                   out0, out1, out2);
}

// Round 2
// 355.403 us; speedup vs baseline: 1.2291x; 1.2291x over previous
//
#include <hip/hip_runtime.h>

typedef float f32x4 __attribute__((ext_vector_type(4)));
typedef short s16x4 __attribute__((ext_vector_type(4)));
typedef short s16x8 __attribute__((ext_vector_type(8)));

__device__ __forceinline__ short f2bf(float f) {
    union { float f; unsigned u; } c; c.f = f;
    return (short)((c.u + 0x7FFFu + ((c.u >> 16) & 1u)) >> 16);
}

// 16B-granular XOR swizzle on a short index (byte ^= ((row&7)<<4)).
// Keeps aligned 4/8-short groups contiguous (XOR touches bits >=3 only).
__device__ __forceinline__ int swz128(int row, int col) {
    return row * 128 + (col ^ ((row & 7) << 3));
}
__device__ __forceinline__ int swz64(int row, int col) {
    return row * 64 + (col ^ ((row & 7) << 3));
}

// ---- prep: transpose 5 fp32 [k][n] weights into bf16 [n][k] in workspace ----
__global__ __launch_bounds__(256) void k_prep(
    const float* __restrict__ Wq, const float* __restrict__ Wk,
    const float* __restrict__ Wv, const float* __restrict__ Wot,
    const float* __restrict__ Wtg, short* __restrict__ Wt) {
    const float* srcs[5] = {Wq, Wk, Wv, Wot, Wtg};
    const float* W = srcs[blockIdx.x];
    short* dst = Wt + blockIdx.x * 16384;
    const int t = threadIdx.x;
#pragma unroll 4
    for (int i = 0; i < 64; ++i) {
        int idx = i * 256 + t;
        int k = idx >> 7, n = idx & 127;
        dst[n * 128 + k] = f2bf(W[idx]);
    }
}

// B-fragment from pre-transposed bf16 weight: Wt[n][k], n=ni*16+m, k=kk*32+quad*8
__device__ __forceinline__ s16x8 wfrag(const short* __restrict__ Wt,
                                       int ni, int kk, int m, int quad) {
    return *(const s16x8*)(Wt + (ni * 16 + m) * 128 + kk * 32 + quad * 8);
}

__global__ __launch_bounds__(256, 2) void k_main(
    const float* __restrict__ XQ, const float* __restrict__ XK,
    const float* __restrict__ Tgt, const short* __restrict__ Wt,
    const float* __restrict__ bq, const float* __restrict__ bk,
    const float* __restrict__ bv, const float* __restrict__ bot,
    const float* __restrict__ btg,
    const float* __restrict__ g_time, const float* __restrict__ b_time,
    const float* __restrict__ g_tgt, const float* __restrict__ b_tgt,
    float* __restrict__ out0, float* __restrict__ out1, float* __restrict__ out2) {
    const int bn = blockIdx.x;
    const int t = threadIdx.x;
    const int w = t >> 6, lane = t & 63, m = lane & 15, quad = lane >> 4;
    const int r0 = w * 16;  // this wave's 16-row band

    // 72 KiB total -> 2 blocks/CU (occupancy is NOT the lever; barriers are).
    __shared__ short BQ[64 * 128];    // XQ stage -> q (own band) -> tv
    __shared__ short BK[64 * 128];    // XK stage -> k            -> ct
    __shared__ short BV[128 * 64];    // v^T [d][key]
    __shared__ short BT[128 * 64];    // Tgt^T [d][key], ALL heads, staged once
    __shared__ short BS[4][16 * 64];  // per-wave S band (private, no barrier)

    const size_t base = (size_t)bn * 8192;
    const short* Wqt = Wt;
    const short* Wkt = Wt + 16384;
    const short* Wvt = Wt + 32768;
    const short* Wot_t = Wt + 49152;
    const short* Wtg_t = Wt + 65536;
    short* myS = BS[w];

    // ---------- stage ALL inputs up front (one latency exposure) ------------
    // XQ, XK: fp32 [64][128] -> bf16 row-major (swz128).
    // Tgt:    fp32 [64][128] -> bf16 transposed [d][key] (swz64).
    {
        const float* sq = XQ + base;
        const float* sk = XK + base;
        const float* st = Tgt + base;
#pragma unroll
        for (int it = 0; it < 8; ++it) {
            int e = t + it * 256;  // float4 index
            int row = e >> 5, c4 = (e & 31) * 4;
            f32x4 xq = *(const f32x4*)(sq + e * 4);
            f32x4 xk = *(const f32x4*)(sk + e * 4);
            f32x4 xt = *(const f32x4*)(st + e * 4);
            s16x4 pq, pk;
#pragma unroll
            for (int r = 0; r < 4; ++r) { pq[r] = f2bf(xq[r]); pk[r] = f2bf(xk[r]); }
            *(s16x4*)(BQ + swz128(row, c4)) = pq;
            *(s16x4*)(BK + swz128(row, c4)) = pk;
#pragma unroll
            for (int r = 0; r < 4; ++r) BT[swz64(c4 + r, row)] = f2bf(xt[r]);
        }
    }
    __syncthreads();  // barrier #1: all staged input visible

    // ---------- q = XQ@Wq + bq -> own BQ band -> qf regs (wave-private) -----
    s16x8 qf[8];
    {
        s16x8 a[4];
#pragma unroll
        for (int kk = 0; kk < 4; ++kk)
            a[kk] = *(const s16x8*)(BQ + swz128(r0 + m, kk * 32 + quad * 8));
        f32x4 accq[8];
#pragma unroll
        for (int ni = 0; ni < 8; ++ni) {
            accq[ni] = (f32x4){0.f, 0.f, 0.f, 0.f};
#pragma unroll
            for (int kk = 0; kk < 4; ++kk)
                accq[ni] = __builtin_amdgcn_mfma_f32_16x16x32_bf16(
                    a[kk], wfrag(Wqt, ni, kk, m, quad), accq[ni], 0, 0, 0);
        }
#pragma unroll
        for (int ni = 0; ni < 8; ++ni) {
            const float bb = bq[ni * 16 + m];
#pragma unroll
            for (int r = 0; r < 4; ++r)
                BQ[swz128(r0 + quad * 4 + r, ni * 16 + m)] = f2bf(accq[ni][r] + bb);
        }
#pragma unroll
        for (int h = 0; h < 8; ++h) {
            qf[h] = (s16x8){0, 0, 0, 0, 0, 0, 0, 0};
            if (quad < 2)
                qf[h] = *(const s16x8*)(BQ + swz128(r0 + m, h * 16 + quad * 8));
        }
    }

    // ---------- k = XK@Wk + bk (own BK band), v^T -> BV ---------------------
    {
        s16x8 a[4];
#pragma unroll
        for (int kk = 0; kk < 4; ++kk)
            a[kk] = *(const s16x8*)(BK + swz128(r0 + m, kk * 32 + quad * 8));
        f32x4 acck[8], accv[8];
#pragma unroll
        for (int ni = 0; ni < 8; ++ni) {
            acck[ni] = (f32x4){0.f, 0.f, 0.f, 0.f};
            accv[ni] = (f32x4){0.f, 0.f, 0.f, 0.f};
#pragma unroll
            for (int kk = 0; kk < 4; ++kk) {
                acck[ni] = __builtin_amdgcn_mfma_f32_16x16x32_bf16(
                    a[kk], wfrag(Wkt, ni, kk, m, quad), acck[ni], 0, 0, 0);
                accv[ni] = __builtin_amdgcn_mfma_f32_16x16x32_bf16(
                    a[kk], wfrag(Wvt, ni, kk, m, quad), accv[ni], 0, 0, 0);
            }
        }
#pragma unroll
        for (int ni = 0; ni < 8; ++ni) {
            const float bbk = bk[ni * 16 + m];
            const float bbv = bv[ni * 16 + m];
#pragma unroll
            for (int r = 0; r < 4; ++r) {
                BK[swz128(r0 + quad * 4 + r, ni * 16 + m)] = f2bf(acck[ni][r] + bbk);
                BV[swz64(ni * 16 + m, r0 + quad * 4 + r)] = f2bf(accv[ni][r] + bbv);
            }
        }
    }
    __syncthreads();  // barrier #2: k, v^T visible; head loop is barrier-FREE

    // ---------- per-head: S = q k^T / 4 ; tv += S v ; ct += S tk ------------
    // BK/BV/BT read-only, BS wave-private, out0 stores stream (never drained).
    f32x4 accv8[8], acct8[8];
    const s16x8 zfrag = (s16x8){0, 0, 0, 0, 0, 0, 0, 0};
    float* o0 = out0 + (size_t)bn * 32768;
#pragma unroll
    for (int h = 0; h < 8; ++h) {
        const s16x8 aq = qf[h];
#pragma unroll
        for (int nj = 0; nj < 4; ++nj) {
            s16x8 bk_ = zfrag;
            if (quad < 2)
                bk_ = *(const s16x8*)(BK + swz128(nj * 16 + m, h * 16 + quad * 8));
            f32x4 s = __builtin_amdgcn_mfma_f32_16x16x32_bf16(
                aq, bk_, (f32x4){0.f, 0.f, 0.f, 0.f}, 0, 0, 0);
#pragma unroll
            for (int r = 0; r < 4; ++r) {
                const int row = r0 + quad * 4 + r;
                const float sval = s[r] * 0.25f;
                o0[h * 4096 + row * 64 + nj * 16 + m] = sval;
                myS[swz64(quad * 4 + r, nj * 16 + m)] = f2bf(sval);
            }
        }
        accv8[h] = (f32x4){0.f, 0.f, 0.f, 0.f};
        acct8[h] = (f32x4){0.f, 0.f, 0.f, 0.f};
#pragma unroll
        for (int kk = 0; kk < 2; ++kk) {
            s16x8 sa  = *(const s16x8*)(myS + swz64(m, kk * 32 + quad * 8));
            s16x8 bv_ = *(const s16x8*)(BV + swz64(h * 16 + m, kk * 32 + quad * 8));
            s16x8 bt_ = *(const s16x8*)(BT + swz64(h * 16 + m, kk * 32 + quad * 8));
            accv8[h] = __builtin_amdgcn_mfma_f32_16x16x32_bf16(sa, bv_, accv8[h], 0, 0, 0);
            acct8[h] = __builtin_amdgcn_mfma_f32_16x16x32_bf16(sa, bt_, acct8[h], 0, 0, 0);
        }
    }
    __syncthreads();  // barrier #3: all cross-wave BK/BV reads done before reuse

    // ---------- tv -> BQ band, ct -> BK band (own band, no barrier) ---------
#pragma unroll
    for (int h = 0; h < 8; ++h) {
#pragma unroll
        for (int r = 0; r < 4; ++r) {
            const int row = r0 + quad * 4 + r;
            BQ[swz128(row, h * 16 + m)] = f2bf(accv8[h][r]);
            BK[swz128(row, h * 16 + m)] = f2bf(acct8[h][r]);
        }
    }

    // ---------- output projections + LayerNorm ------------------------------
#pragma unroll
    for (int br = 0; br < 2; ++br) {
        const short* sA = br == 0 ? BQ : BK;
        const short* Wp = br == 0 ? Wot_t : Wtg_t;
        const float* bias = br == 0 ? bot : btg;
        const float* gam = br == 0 ? g_time : g_tgt;
        const float* bet = br == 0 ? b_time : b_tgt;
        float* outp = (br == 0 ? out1 : out2) + base;
        const float* resid = br == 0 ? XQ + base : nullptr;

        s16x8 a[4];
#pragma unroll
        for (int kk = 0; kk < 4; ++kk)
            a[kk] = *(const s16x8*)(sA + swz128(r0 + m, kk * 32 + quad * 8));
        f32x4 acc[8];
#pragma unroll
        for (int ni = 0; ni < 8; ++ni) {
            acc[ni] = (f32x4){0.f, 0.f, 0.f, 0.f};
#pragma unroll
            for (int kk = 0; kk < 4; ++kk)
                acc[ni] = __builtin_amdgcn_mfma_f32_16x16x32_bf16(
                    a[kk], wfrag(Wp, ni, kk, m, quad), acc[ni], 0, 0, 0);
        }
        float y[8][4];
        float s1[4] = {0.f, 0.f, 0.f, 0.f}, s2[4] = {0.f, 0.f, 0.f, 0.f};
#pragma unroll
        for (int ni = 0; ni < 8; ++ni) {
            const int col = ni * 16 + m;
            const float bb = bias[col];
#pragma unroll
            for (int r = 0; r < 4; ++r) {
                const int row = r0 + quad * 4 + r;
                float v = acc[ni][r] + bb;
                if (resid) v += resid[row * 128 + col];
                y[ni][r] = v;
                s1[r] += v;
                s2[r] += v * v;
            }
        }
#pragma unroll
        for (int mask = 1; mask < 16; mask <<= 1) {
#pragma unroll
            for (int r = 0; r < 4; ++r) {
                s1[r] += __shfl_xor(s1[r], mask, 64);
                s2[r] += __shfl_xor(s2[r], mask, 64);
            }
        }
        float mu[4], rstd[4];
#pragma unroll
        for (int r = 0; r < 4; ++r) {
            mu[r] = s1[r] * (1.0f / 128.0f);
            float var = s2[r] * (1.0f / 128.0f) - mu[r] * mu[r];
            rstd[r] = rsqrtf(var + 1e-5f);
        }
#pragma unroll
        for (int ni = 0; ni < 8; ++ni) {
            const int col = ni * 16 + m;
            const float g = gam[col], bb = bet[col];
#pragma unroll
            for (int r = 0; r < 4; ++r) {
                const int row = r0 + quad * 4 + r;
                outp[row * 128 + col] = (y[ni][r] - mu[r]) * rstd[r] * g + bb;
            }
        }
    }
}

extern "C" void kernel_launch(void* const* d_in, const int* in_sizes, int n_in,
                              void* d_out, int out_size, void* d_ws, size_t ws_size,
                              hipStream_t stream) {
    const float* XQ  = (const float*)d_in[0];
    const float* XK  = (const float*)d_in[1];
    const float* Tgt = (const float*)d_in[2];
    const float* Wq  = (const float*)d_in[3];
    const float* bq  = (const float*)d_in[4];
    const float* Wk  = (const float*)d_in[5];
    const float* bk  = (const float*)d_in[6];
    const float* Wv  = (const float*)d_in[7];
    const float* bv  = (const float*)d_in[8];
    const float* Wot = (const float*)d_in[9];
    const float* bot = (const float*)d_in[10];
    const float* Wtg = (const float*)d_in[11];
    const float* btg = (const float*)d_in[12];
    const float* g_time = (const float*)d_in[13];
    const float* b_time = (const float*)d_in[14];
    const float* g_tgt  = (const float*)d_in[15];
    const float* b_tgt  = (const float*)d_in[16];

    const int BN = in_sizes[0] / 8192;  // B*N

    short* Wt = (short*)d_ws;  // 5 * 128 * 128 bf16 = 160 KB

    float* out0 = (float*)d_out;
    float* out1 = out0 + (size_t)BN * 32768;
    float* out2 = out1 + (size_t)BN * 8192;

    k_prep<<<5, 256, 0, stream>>>(Wq, Wk, Wv, Wot, Wtg, Wt);
    k_main<<<BN, 256, 0, stream>>>(XQ, XK, Tgt, Wt, bq, bk, bv, bot, btg,
                                   g_time, b_time, g_tgt, b_tgt,
                                   out0, out1, out2);
}